// Round 12
// baseline (352.662 us; speedup 1.0000x reference)
//
#include <hip/hip_runtime.h>

#define Bn 4
#define Hn 16
#define Sn 2048
#define Dn 64
#define NT (Sn / 64)
#define BLOB 24576
#define WS_NEED ((size_t)Bn * Hn * NT * BLOB)

typedef __attribute__((ext_vector_type(8))) short bf16x8;
typedef __attribute__((ext_vector_type(4))) float f32x4;
typedef __attribute__((ext_vector_type(4))) float float4_t;
typedef __attribute__((ext_vector_type(2))) unsigned u32x2;

__device__ __forceinline__ short f2bf(float f) {
    union { float f; unsigned u; } v; v.f = f;
    unsigned r = v.u + 0x7fffu + ((v.u >> 16) & 1u);
    return (short)(r >> 16);
}
__device__ __forceinline__ float bf2f(short h) {
    union { unsigned u; float f; } v; v.u = ((unsigned)(unsigned short)h) << 16;
    return v.f;
}
__device__ __forceinline__ unsigned cvtpk_bf16(float a, float b) {
    unsigned d;
    asm("v_cvt_pk_bf16_f32 %0, %1, %2" : "=v"(d) : "v"(a), "v"(b));
    return d;
}

// ---------------- pre-pass (R8 layout): K -> (hi,lo) bf16, V -> V^T bf16, LDS-image ----------------
// blob[bh*NT + t] (24 KB): [0,8K) K-hi swizzled, [8K,16K) K-lo swizzled, [16K,24K) V^T swizzled
__global__ __launch_bounds__(256) void prepass_kernel(
    const float* __restrict__ K, const float* __restrict__ V, char* __restrict__ ws)
{
    const int tid = threadIdx.x;
    const int kv0 = (blockIdx.x & (NT - 1)) * 64;
    char* blob = ws + (size_t)blockIdx.x * BLOB;
    const size_t kv_base = (size_t)(blockIdx.x >> 5) * Sn * Dn;

    {
        const int r  = tid >> 2;
        const int dc = (tid & 3) * 16;
        const float* krow = K + kv_base + (size_t)(kv0 + r) * Dn + dc;
        float4_t k0 = ((const float4_t*)krow)[0];
        float4_t k1 = ((const float4_t*)krow)[1];
        float4_t k2 = ((const float4_t*)krow)[2];
        float4_t k3 = ((const float4_t*)krow)[3];
        float fv[16] = {k0[0],k0[1],k0[2],k0[3], k1[0],k1[1],k1[2],k1[3],
                        k2[0],k2[1],k2[2],k2[3], k3[0],k3[1],k3[2],k3[3]};
        bf16x8 ha, hb, la, lb;
#pragma unroll
        for (int j = 0; j < 8; ++j) {
            short h = f2bf(fv[j]);
            ha[j] = h; la[j] = f2bf(fv[j] - bf2f(h));
            short h2 = f2bf(fv[j + 8]);
            hb[j] = h2; lb[j] = f2bf(fv[j + 8] - bf2f(h2));
        }
        const unsigned base = (unsigned)(r * 128 + dc * 2);
        const unsigned swz  = (unsigned)((r & 7) << 4);
        *(bf16x8*)(blob + ((base) ^ swz))             = ha;
        *(bf16x8*)(blob + ((base + 16) ^ swz))        = hb;
        *(bf16x8*)(blob + 8192 + ((base) ^ swz))      = la;
        *(bf16x8*)(blob + 8192 + ((base + 16) ^ swz)) = lb;
    }
    {
        const int r2 = (tid & 31) * 2;
        const int d0 = (tid >> 5) * 8;
        const float* v0 = V + kv_base + (size_t)(kv0 + r2) * Dn + d0;
        float4_t a0 = ((const float4_t*)v0)[0];
        float4_t a1 = ((const float4_t*)v0)[1];
        float4_t b0 = ((const float4_t*)(v0 + Dn))[0];
        float4_t b1 = ((const float4_t*)(v0 + Dn))[1];
        float av[8] = {a0[0],a0[1],a0[2],a0[3], a1[0],a1[1],a1[2],a1[3]};
        float bv[8] = {b0[0],b0[1],b0[2],b0[3], b1[0],b1[1],b1[2],b1[3]};
#pragma unroll
        for (int j = 0; j < 8; ++j) {
            const int d = d0 + j;
            unsigned wv = ((unsigned)(unsigned short)f2bf(av[j]))
                        | (((unsigned)(unsigned short)f2bf(bv[j])) << 16);
            unsigned off = ((unsigned)(d * 128 + r2 * 2)) ^ ((unsigned)((d & 7) << 4));
            *(unsigned*)(blob + 16384 + off) = wv;
        }
    }
}

// ---------------- main attention kernel: R11 (swapped QK^T) + bh-major grid ----------------
// grid(bh=64, q=32): linear id % 8 == bh % 8 -> all 32 q-blocks of one bh on one XCD.
// The 24 KB blob-tile is HBM-fetched by the first reader and L2-hit by the other ~31 blocks:
// ws HBM re-read traffic 1.57 GB -> ~50 MB, leaving the 1.07 GB mask stream dominant.
// Everything else identical to R11 (swapped S^T layout, cvt_pk P-writes, counted barrier).
__global__ __launch_bounds__(256) void attn_main_kernel(
    const float* __restrict__ Q, const float* __restrict__ Msk,
    const char* __restrict__ ws, float* __restrict__ Out)
{
    __shared__ char lds_kv[2][BLOB];               // double-buffered tile blob
    __shared__ unsigned short lds_p[4][16 * 64];   // per-wave P tile (wave-private)
    __shared__ float lds_l[4][16];                 // per-wave denom redistribute (epilogue)

    const int tid  = threadIdx.x;
    const int lane = tid & 63;
    const int w    = tid >> 6;
    const int lq   = lane & 15;
    const int lg   = lane >> 4;

    const int bh = blockIdx.x;          // bh-major: XCD = bh % 8
    const int q0 = blockIdx.y * 64;

    const float* qp   = Q + (size_t)bh * Sn * Dn;
    const float* mrow = Msk + (size_t)bh * Sn * Sn + (size_t)(q0 + w * 16 + lq) * Sn;
    const char* ws_bh = ws + (size_t)bh * NT * BLOB;
    float* op = Out + (size_t)bh * Sn * Dn + (size_t)(q0 + w * 16) * Dn;

    const float QSCALE = 2.0402789f;  // sqrt(2) * log2(e): logits directly in log2 domain

    // ---- Q fragments hi/lo, pre-scaled (serve as MFMA B operand) ----
    bf16x8 qh[2], ql[2];
    {
        const float* qrow = qp + (size_t)(q0 + w * 16 + lq) * Dn + lg * 8;
#pragma unroll
        for (int c = 0; c < 2; ++c) {
            float4_t f0 = *(const float4_t*)(qrow + c * 32);
            float4_t f1 = *(const float4_t*)(qrow + c * 32 + 4);
            float fv[8] = {f0[0], f0[1], f0[2], f0[3], f1[0], f1[1], f1[2], f1[3]};
            bf16x8 th, tl;
#pragma unroll
            for (int j = 0; j < 8; ++j) {
                float x = fv[j] * QSCALE;
                short h = f2bf(x);
                th[j] = h;
                tl[j] = f2bf(x - bf2f(h));
            }
            qh[c] = th; ql[c] = tl;
        }
    }

    float l_acc = 0.0f;   // per-lane partial denominator for q = lq
    f32x4 o_acc[4];
#pragma unroll
    for (int dt = 0; dt < 4; ++dt) o_acc[dt] = (f32x4){0.f, 0.f, 0.f, 0.f};

#define STAGE(TSRC, BUFIDX) do {                                                   \
        const char* _src = ws_bh + (size_t)(TSRC) * BLOB + w * 6144 + lane * 16;   \
        char* _dst = &lds_kv[BUFIDX][w * 6144];                                    \
        _Pragma("unroll")                                                          \
        for (int _i = 0; _i < 6; ++_i) {                                           \
            __builtin_amdgcn_global_load_lds(                                      \
                (const __attribute__((address_space(1))) void*)(_src + _i * 1024), \
                (__attribute__((address_space(3))) void*)(_dst + _i * 1024),       \
                16, 0, 0);                                                         \
        }                                                                          \
    } while (0)

// mask[q=lq][kv = T*64 + kt*16 + lg*4 .. +3] as one dwordx4 per kt
#define LOADMASK(MREG, TSRC) do {                                                  \
        _Pragma("unroll")                                                          \
        for (int _kt = 0; _kt < 4; ++_kt)                                          \
            MREG[_kt] = *(const float4_t*)(mrow + (TSRC) * 64 + _kt * 16 + lg * 4);\
    } while (0)

// counted barrier: drain staging (6 oldest VMEM), keep 4 mask loads in flight
#define TILE_BARRIER() do {                                                        \
        asm volatile("s_waitcnt vmcnt(4)\n\ts_barrier" ::: "memory");              \
        __builtin_amdgcn_sched_barrier(0);                                         \
    } while (0)

#define ITER_BODY(T, BUF, MU, MP) do {                                                   \
        TILE_BARRIER(); /* staging(T) drained; mask(T) still in flight */                \
        if ((T) + 1 < NT) {                                                              \
            STAGE((T) + 1, (BUF) ^ 1);                                                   \
            __builtin_amdgcn_sched_barrier(0); /* pin: staging before mask loads */      \
            LOADMASK(MP, (T) + 1);                                                       \
            __builtin_amdgcn_sched_barrier(0); /* pin: mask loads issued here */         \
        }                                                                                \
        const char* kb = lds_kv[BUF];                                                    \
        f32x4 s[4];                                                                      \
        _Pragma("unroll")                                                                \
        for (int kt = 0; kt < 4; ++kt) {                                                 \
            f32x4 acc = (f32x4){0.f, 0.f, 0.f, 0.f};                                     \
            _Pragma("unroll")                                                            \
            for (int c = 0; c < 2; ++c) {                                                \
                const int krow = kt * 16 + lq;                                           \
                unsigned off = ((unsigned)(krow * 128 + (c * 32 + lg * 8) * 2))          \
                             ^ ((unsigned)((krow & 7) << 4));                            \
                bf16x8 khf = *(const bf16x8*)(kb + off);                                 \
                bf16x8 klf = *(const bf16x8*)(kb + 8192 + off);                          \
                /* swapped operands: S^T = K * Q^T */                                    \
                acc = __builtin_amdgcn_mfma_f32_16x16x32_bf16(khf, qh[c], acc, 0, 0, 0); \
                acc = __builtin_amdgcn_mfma_f32_16x16x32_bf16(klf, qh[c], acc, 0, 0, 0); \
                acc = __builtin_amdgcn_mfma_f32_16x16x32_bf16(khf, ql[c], acc, 0, 0, 0); \
            }                                                                            \
            s[kt] = acc;                                                                 \
        }                                                                                \
        /* fixed-base softmax numerator + mask -> P (4 consecutive kv per kt, b64) */    \
        {                                                                                \
            unsigned short* pw = &lds_p[w][0];                                           \
            const unsigned pswz = (unsigned)((lq & 7) << 4);                             \
            _Pragma("unroll")                                                            \
            for (int kt = 0; kt < 4; ++kt) {                                             \
                float p0 = exp2f(s[kt][0]);                                              \
                float p1 = exp2f(s[kt][1]);                                              \
                float p2 = exp2f(s[kt][2]);                                              \
                float p3 = exp2f(s[kt][3]);                                              \
                l_acc += (p0 + p1) + (p2 + p3);                                          \
                unsigned w0 = cvtpk_bf16(p0 * MU[kt][0], p1 * MU[kt][1]);                \
                unsigned w1 = cvtpk_bf16(p2 * MU[kt][2], p3 * MU[kt][3]);                \
                unsigned off = ((unsigned)(lq * 128 + kt * 32 + lg * 8)) ^ pswz;         \
                u32x2 wv; wv[0] = w0; wv[1] = w1;                                        \
                *(u32x2*)((char*)pw + off) = wv;                                         \
            }                                                                            \
        }                                                                                \
        /* PV: P from wave-private LDS (b128), V^T frags from LDS */                     \
        _Pragma("unroll")                                                                \
        for (int kc = 0; kc < 2; ++kc) {                                                 \
            unsigned poff = ((unsigned)(lq * 128 + (kc * 32 + lg * 8) * 2))              \
                          ^ ((unsigned)((lq & 7) << 4));                                 \
            bf16x8 pa = *(const bf16x8*)((const char*)&lds_p[w][0] + poff);              \
            _Pragma("unroll")                                                            \
            for (int dt = 0; dt < 4; ++dt) {                                             \
                const int drow = dt * 16 + lq;                                           \
                unsigned voff = 16384 +                                                  \
                    (((unsigned)(drow * 128 + (kc * 32 + lg * 8) * 2))                   \
                     ^ ((unsigned)((drow & 7) << 4)));                                   \
                bf16x8 vb = *(const bf16x8*)(kb + voff);                                 \
                o_acc[dt] = __builtin_amdgcn_mfma_f32_16x16x32_bf16(pa, vb, o_acc[dt],   \
                                                                    0, 0, 0);            \
            }                                                                            \
        }                                                                                \
    } while (0)

    float4_t mA[4], mB[4];
    STAGE(0, 0);
    __builtin_amdgcn_sched_barrier(0);
    LOADMASK(mA, 0);
    __builtin_amdgcn_sched_barrier(0);

    for (int t = 0; t < NT; t += 2) {
        ITER_BODY(t, 0, mA, mB);
        ITER_BODY(t + 1, 1, mB, mA);
    }

    // ---- epilogue: l lives at q=lq; reduce across lg, redistribute to o_acc rows ----
    l_acc += __shfl_xor(l_acc, 16);
    l_acc += __shfl_xor(l_acc, 32);
    if (lane < 16) lds_l[w][lane] = l_acc;
    __builtin_amdgcn_sched_barrier(0);
#pragma unroll
    for (int r = 0; r < 4; ++r) {
        const float inv = 1.0f / lds_l[w][lg * 4 + r];
#pragma unroll
        for (int dt = 0; dt < 4; ++dt) {
            op[(size_t)(lg * 4 + r) * Dn + dt * 16 + lq] = o_acc[dt][r] * inv;
        }
    }
#undef STAGE
#undef LOADMASK
#undef TILE_BARRIER
#undef ITER_BODY
}

// ---------------- fallback (self-contained, used if ws too small) ----------------
__global__ __launch_bounds__(256) void attn_drop_fallback(
    const float* __restrict__ Q, const float* __restrict__ K,
    const float* __restrict__ V, const float* __restrict__ Msk,
    float* __restrict__ Out)
{
    __shared__ unsigned short lds_kh[64 * 64];
    __shared__ unsigned short lds_kl[64 * 64];
    __shared__ unsigned short lds_v[64 * 64];
    __shared__ unsigned short lds_p[4][16 * 64];

    const int tid  = threadIdx.x;
    const int lane = tid & 63;
    const int w    = tid >> 6;
    const int lq   = lane & 15;
    const int lg   = lane >> 4;
    const int q0 = blockIdx.x * 64;
    const int bh = blockIdx.y;
    const size_t qkv_base = (size_t)bh * Sn * Dn;
    const float* qp = Q + qkv_base;
    const float* kp = K + qkv_base;
    const float* vp = V + qkv_base;
    const float* mbase = Msk + (size_t)bh * Sn * Sn + (size_t)(q0 + w * 16) * Sn;
    float* op = Out + qkv_base + (size_t)(q0 + w * 16) * Dn;
    const float SQRT2 = 1.41421356237f;
    const float LOG2E = 1.44269504089f;

    bf16x8 qh[2], ql[2];
    {
        const float* qrow = qp + (size_t)(q0 + w * 16 + lq) * Dn + lg * 8;
#pragma unroll
        for (int c = 0; c < 2; ++c) {
            float4_t f0 = *(const float4_t*)(qrow + c * 32);
            float4_t f1 = *(const float4_t*)(qrow + c * 32 + 4);
            float fv[8] = {f0[0], f0[1], f0[2], f0[3], f1[0], f1[1], f1[2], f1[3]};
            bf16x8 th, tl;
#pragma unroll
            for (int j = 0; j < 8; ++j) {
                short h = f2bf(fv[j]);
                th[j] = h; tl[j] = f2bf(fv[j] - bf2f(h));
            }
            qh[c] = th; ql[c] = tl;
        }
    }
    float m_st[4], l_st[4];
    f32x4 o_acc[4];
#pragma unroll
    for (int r = 0; r < 4; ++r) { m_st[r] = -INFINITY; l_st[r] = 0.0f; }
#pragma unroll
    for (int dt = 0; dt < 4; ++dt) o_acc[dt] = (f32x4){0.f, 0.f, 0.f, 0.f};

    for (int t = 0; t < NT; ++t) {
        const int kv0 = t * 64;
        __syncthreads();
        {
            const int r  = tid >> 2;
            const int dc = (tid & 3) * 16;
            const float* krow = kp + (size_t)(kv0 + r) * Dn + dc;
            float4_t k0 = ((const float4_t*)krow)[0];
            float4_t k1 = ((const float4_t*)krow)[1];
            float4_t k2 = ((const float4_t*)krow)[2];
            float4_t k3 = ((const float4_t*)krow)[3];
            float fv[16] = {k0[0],k0[1],k0[2],k0[3], k1[0],k1[1],k1[2],k1[3],
                            k2[0],k2[1],k2[2],k2[3], k3[0],k3[1],k3[2],k3[3]};
            bf16x8 ha, hb, la, lb;
#pragma unroll
            for (int j = 0; j < 8; ++j) {
                short h = f2bf(fv[j]);
                ha[j] = h; la[j] = f2bf(fv[j] - bf2f(h));
                short h2 = f2bf(fv[j + 8]);
                hb[j] = h2; lb[j] = f2bf(fv[j + 8] - bf2f(h2));
            }
            const unsigned base = (unsigned)(r * 128 + dc * 2);
            const unsigned swz  = (unsigned)((r & 7) << 4);
            *(bf16x8*)((char*)lds_kh + ((base) ^ swz))      = ha;
            *(bf16x8*)((char*)lds_kh + ((base + 16) ^ swz)) = hb;
            *(bf16x8*)((char*)lds_kl + ((base) ^ swz))      = la;
            *(bf16x8*)((char*)lds_kl + ((base + 16) ^ swz)) = lb;
        }
        {
            const int r2 = (tid & 31) * 2;
            const int d0 = (tid >> 5) * 8;
            const float* v0 = vp + (size_t)(kv0 + r2) * Dn + d0;
            float4_t a0 = ((const float4_t*)v0)[0];
            float4_t a1 = ((const float4_t*)v0)[1];
            float4_t b0 = ((const float4_t*)(v0 + Dn))[0];
            float4_t b1 = ((const float4_t*)(v0 + Dn))[1];
            float av[8] = {a0[0],a0[1],a0[2],a0[3], a1[0],a1[1],a1[2],a1[3]};
            float bv[8] = {b0[0],b0[1],b0[2],b0[3], b1[0],b1[1],b1[2],b1[3]};
#pragma unroll
            for (int j = 0; j < 8; ++j) {
                const int d = d0 + j;
                unsigned wv = ((unsigned)(unsigned short)f2bf(av[j]))
                            | (((unsigned)(unsigned short)f2bf(bv[j])) << 16);
                unsigned off = ((unsigned)(d * 128 + r2 * 2)) ^ ((unsigned)((d & 7) << 4));
                *(unsigned*)((char*)lds_v + off) = wv;
            }
        }
        __syncthreads();
        f32x4 s[4];
#pragma unroll
        for (int kt = 0; kt < 4; ++kt) {
            f32x4 acc = (f32x4){0.f, 0.f, 0.f, 0.f};
#pragma unroll
            for (int c = 0; c < 2; ++c) {
                const int krow = kt * 16 + lq;
                unsigned off = ((unsigned)(krow * 128 + (c * 32 + lg * 8) * 2))
                             ^ ((unsigned)((krow & 7) << 4));
                bf16x8 khf = *(const bf16x8*)((const char*)lds_kh + off);
                bf16x8 klf = *(const bf16x8*)((const char*)lds_kl + off);
                acc = __builtin_amdgcn_mfma_f32_16x16x32_bf16(qh[c], khf, acc, 0, 0, 0);
                acc = __builtin_amdgcn_mfma_f32_16x16x32_bf16(qh[c], klf, acc, 0, 0, 0);
                acc = __builtin_amdgcn_mfma_f32_16x16x32_bf16(ql[c], khf, acc, 0, 0, 0);
            }
            s[kt] = acc * SQRT2;
        }
        float pbuf[4][4];
#pragma unroll
        for (int r = 0; r < 4; ++r) {
            float mx = fmaxf(fmaxf(s[0][r], s[1][r]), fmaxf(s[2][r], s[3][r]));
            mx = fmaxf(mx, __shfl_xor(mx, 1));
            mx = fmaxf(mx, __shfl_xor(mx, 2));
            mx = fmaxf(mx, __shfl_xor(mx, 4));
            mx = fmaxf(mx, __shfl_xor(mx, 8));
            const float mnew = fmaxf(m_st[r], mx);
            const float corr = exp2f((m_st[r] - mnew) * LOG2E);
            m_st[r] = mnew;
            float psum = 0.f;
#pragma unroll
            for (int kt = 0; kt < 4; ++kt) {
                float p = exp2f((s[kt][r] - mnew) * LOG2E);
                pbuf[kt][r] = p;
                psum += p;
            }
            l_st[r] = l_st[r] * corr + psum;
#pragma unroll
            for (int dt = 0; dt < 4; ++dt) o_acc[dt][r] *= corr;
        }
        {
            unsigned short* pw = &lds_p[w][0];
#pragma unroll
            for (int r = 0; r < 4; ++r) {
                const int row = lg * 4 + r;
                const float* mp = mbase + (size_t)row * Sn + kv0;
#pragma unroll
                for (int kt = 0; kt < 4; ++kt) {
                    float mv = mp[kt * 16 + lq];
                    float pm = pbuf[kt][r] * mv;
                    unsigned off = ((unsigned)(row * 128 + (kt * 16 + lq) * 2))
                                 ^ ((unsigned)((row & 7) << 4));
                    *(unsigned short*)((char*)pw + off) = (unsigned short)f2bf(pm);
                }
            }
        }
        __syncthreads();
#pragma unroll
        for (int kc = 0; kc < 2; ++kc) {
            unsigned poff = ((unsigned)(lq * 128 + (kc * 32 + lg * 8) * 2))
                          ^ ((unsigned)((lq & 7) << 4));
            bf16x8 pa = *(const bf16x8*)((const char*)&lds_p[w][0] + poff);
#pragma unroll
            for (int dt = 0; dt < 4; ++dt) {
                const int drow = dt * 16 + lq;
                unsigned voff = ((unsigned)(drow * 128 + (kc * 32 + lg * 8) * 2))
                              ^ ((unsigned)((drow & 7) << 4));
                bf16x8 vb = *(const bf16x8*)((const char*)lds_v + voff);
                o_acc[dt] = __builtin_amdgcn_mfma_f32_16x16x32_bf16(pa, vb, o_acc[dt], 0, 0, 0);
            }
        }
    }
#pragma unroll
    for (int r = 0; r < 4; ++r) {
        float ls = l_st[r];
        ls += __shfl_xor(ls, 1);
        ls += __shfl_xor(ls, 2);
        ls += __shfl_xor(ls, 4);
        ls += __shfl_xor(ls, 8);
        const float inv = 1.0f / ls;
#pragma unroll
        for (int dt = 0; dt < 4; ++dt) {
            op[(size_t)(lg * 4 + r) * Dn + dt * 16 + lq] = o_acc[dt][r] * inv;
        }
    }
}

extern "C" void kernel_launch(void* const* d_in, const int* in_sizes, int n_in,
                              void* d_out, int out_size, void* d_ws, size_t ws_size,
                              hipStream_t stream) {
    const float* q   = (const float*)d_in[0];
    const float* k   = (const float*)d_in[1];
    const float* v   = (const float*)d_in[2];
    const float* msk = (const float*)d_in[3];
    float* out = (float*)d_out;

    if (ws_size >= WS_NEED) {
        prepass_kernel<<<dim3(Bn * Hn * NT), dim3(256), 0, stream>>>(k, v, (char*)d_ws);
        // bh-major grid: XCD = linear % 8 = bh % 8 -> blob L2 locality across q-blocks
        attn_main_kernel<<<dim3(Bn * Hn, Sn / 64), dim3(256), 0, stream>>>(
            q, msk, (const char*)d_ws, out);
    } else {
        attn_drop_fallback<<<dim3(Sn / 64, Bn * Hn), dim3(256), 0, stream>>>(
            q, k, v, msk, out);
    }
}

// Round 13
// 333.044 us; speedup vs baseline: 1.0589x; 1.0589x over previous
//
#include <hip/hip_runtime.h>

#define Bn 4
#define Hn 16
#define Sn 2048
#define Dn 64
#define NT (Sn / 64)
#define BLOB 24576
#define WS_NEED ((size_t)Bn * Hn * NT * BLOB)

typedef __attribute__((ext_vector_type(8))) short bf16x8;
typedef __attribute__((ext_vector_type(4))) float f32x4;
typedef __attribute__((ext_vector_type(4))) float float4_t;
typedef __attribute__((ext_vector_type(2))) unsigned u32x2;

__device__ __forceinline__ short f2bf(float f) {
    union { float f; unsigned u; } v; v.f = f;
    unsigned r = v.u + 0x7fffu + ((v.u >> 16) & 1u);
    return (short)(r >> 16);
}
__device__ __forceinline__ float bf2f(short h) {
    union { unsigned u; float f; } v; v.u = ((unsigned)(unsigned short)h) << 16;
    return v.f;
}
__device__ __forceinline__ unsigned cvtpk_bf16(float a, float b) {
    unsigned d;
    asm("v_cvt_pk_bf16_f32 %0, %1, %2" : "=v"(d) : "v"(a), "v"(b));
    return d;
}

// ---------------- pre-pass (R8 layout): K -> (hi,lo) bf16, V -> V^T bf16, LDS-image ----------------
// blob[bh*NT + t] (24 KB): [0,8K) K-hi swizzled, [8K,16K) K-lo swizzled, [16K,24K) V^T swizzled
__global__ __launch_bounds__(256) void prepass_kernel(
    const float* __restrict__ K, const float* __restrict__ V, char* __restrict__ ws)
{
    const int tid = threadIdx.x;
    const int kv0 = (blockIdx.x & (NT - 1)) * 64;
    char* blob = ws + (size_t)blockIdx.x * BLOB;
    const size_t kv_base = (size_t)(blockIdx.x >> 5) * Sn * Dn;

    {
        const int r  = tid >> 2;
        const int dc = (tid & 3) * 16;
        const float* krow = K + kv_base + (size_t)(kv0 + r) * Dn + dc;
        float4_t k0 = ((const float4_t*)krow)[0];
        float4_t k1 = ((const float4_t*)krow)[1];
        float4_t k2 = ((const float4_t*)krow)[2];
        float4_t k3 = ((const float4_t*)krow)[3];
        float fv[16] = {k0[0],k0[1],k0[2],k0[3], k1[0],k1[1],k1[2],k1[3],
                        k2[0],k2[1],k2[2],k2[3], k3[0],k3[1],k3[2],k3[3]};
        bf16x8 ha, hb, la, lb;
#pragma unroll
        for (int j = 0; j < 8; ++j) {
            short h = f2bf(fv[j]);
            ha[j] = h; la[j] = f2bf(fv[j] - bf2f(h));
            short h2 = f2bf(fv[j + 8]);
            hb[j] = h2; lb[j] = f2bf(fv[j + 8] - bf2f(h2));
        }
        const unsigned base = (unsigned)(r * 128 + dc * 2);
        const unsigned swz  = (unsigned)((r & 7) << 4);
        *(bf16x8*)(blob + ((base) ^ swz))             = ha;
        *(bf16x8*)(blob + ((base + 16) ^ swz))        = hb;
        *(bf16x8*)(blob + 8192 + ((base) ^ swz))      = la;
        *(bf16x8*)(blob + 8192 + ((base + 16) ^ swz)) = lb;
    }
    {
        const int r2 = (tid & 31) * 2;
        const int d0 = (tid >> 5) * 8;
        const float* v0 = V + kv_base + (size_t)(kv0 + r2) * Dn + d0;
        float4_t a0 = ((const float4_t*)v0)[0];
        float4_t a1 = ((const float4_t*)v0)[1];
        float4_t b0 = ((const float4_t*)(v0 + Dn))[0];
        float4_t b1 = ((const float4_t*)(v0 + Dn))[1];
        float av[8] = {a0[0],a0[1],a0[2],a0[3], a1[0],a1[1],a1[2],a1[3]};
        float bv[8] = {b0[0],b0[1],b0[2],b0[3], b1[0],b1[1],b1[2],b1[3]};
#pragma unroll
        for (int j = 0; j < 8; ++j) {
            const int d = d0 + j;
            unsigned wv = ((unsigned)(unsigned short)f2bf(av[j]))
                        | (((unsigned)(unsigned short)f2bf(bv[j])) << 16);
            unsigned off = ((unsigned)(d * 128 + r2 * 2)) ^ ((unsigned)((d & 7) << 4));
            *(unsigned*)(blob + 16384 + off) = wv;
        }
    }
}

// ---------------- main attention kernel: 8 waves / 512 threads share one staged blob ----------------
// Per-wave code = R12 (swapped S^T QK^T, cvt_pk P-writes, fixed-base softmax, counted barrier).
// 8 waves x 16 q-rows = 128 q-rows/block; one 24 KB blob stage serves all 8 waves.
// LDS ~65 KB -> 2 blocks/CU = 16 waves/CU = 4 waves/SIMD (2x TLP vs 256-thread version).
// QK uses 3 independent accumulators (chain depth 6 -> 2) for ILP within the wave.
__global__ __launch_bounds__(512, 4) void attn_main_kernel(
    const float* __restrict__ Q, const float* __restrict__ Msk,
    const char* __restrict__ ws, float* __restrict__ Out)
{
    __shared__ char lds_kv[2][BLOB];               // double-buffered tile blob (shared by 8 waves)
    __shared__ unsigned short lds_p[8][16 * 64];   // per-wave P tile (wave-private)
    __shared__ float lds_l[8][16];                 // per-wave denom redistribute (epilogue)

    const int tid  = threadIdx.x;
    const int lane = tid & 63;
    const int w    = tid >> 6;        // 0..7
    const int lq   = lane & 15;
    const int lg   = lane >> 4;

    const int bh = blockIdx.x;        // bh-major: XCD = bh % 8
    const int q0 = blockIdx.y * 128;  // 128 q-rows per block

    const float* qp   = Q + (size_t)bh * Sn * Dn;
    const float* mrow = Msk + (size_t)bh * Sn * Sn + (size_t)(q0 + w * 16 + lq) * Sn;
    const char* ws_bh = ws + (size_t)bh * NT * BLOB;
    float* op = Out + (size_t)bh * Sn * Dn + (size_t)(q0 + w * 16) * Dn;

    const float QSCALE = 2.0402789f;  // sqrt(2) * log2(e): logits directly in log2 domain

    // ---- Q fragments hi/lo, pre-scaled (MFMA B operand) ----
    bf16x8 qh[2], ql[2];
    {
        const float* qrow = qp + (size_t)(q0 + w * 16 + lq) * Dn + lg * 8;
#pragma unroll
        for (int c = 0; c < 2; ++c) {
            float4_t f0 = *(const float4_t*)(qrow + c * 32);
            float4_t f1 = *(const float4_t*)(qrow + c * 32 + 4);
            float fv[8] = {f0[0], f0[1], f0[2], f0[3], f1[0], f1[1], f1[2], f1[3]};
            bf16x8 th, tl;
#pragma unroll
            for (int j = 0; j < 8; ++j) {
                float x = fv[j] * QSCALE;
                short h = f2bf(x);
                th[j] = h;
                tl[j] = f2bf(x - bf2f(h));
            }
            qh[c] = th; ql[c] = tl;
        }
    }

    float l_acc = 0.0f;   // per-lane partial denominator for q = lq
    f32x4 o_acc[4];
#pragma unroll
    for (int dt = 0; dt < 4; ++dt) o_acc[dt] = (f32x4){0.f, 0.f, 0.f, 0.f};

// 8 waves x 3 KB each = 24 KB blob
#define STAGE(TSRC, BUFIDX) do {                                                   \
        const char* _src = ws_bh + (size_t)(TSRC) * BLOB + w * 3072 + lane * 16;   \
        char* _dst = &lds_kv[BUFIDX][w * 3072];                                    \
        _Pragma("unroll")                                                          \
        for (int _i = 0; _i < 3; ++_i) {                                           \
            __builtin_amdgcn_global_load_lds(                                      \
                (const __attribute__((address_space(1))) void*)(_src + _i * 1024), \
                (__attribute__((address_space(3))) void*)(_dst + _i * 1024),       \
                16, 0, 0);                                                         \
        }                                                                          \
    } while (0)

// mask[q=lq][kv = T*64 + kt*16 + lg*4 .. +3] as one dwordx4 per kt
#define LOADMASK(MREG, TSRC) do {                                                  \
        _Pragma("unroll")                                                          \
        for (int _kt = 0; _kt < 4; ++_kt)                                          \
            MREG[_kt] = *(const float4_t*)(mrow + (TSRC) * 64 + _kt * 16 + lg * 4);\
    } while (0)

// counted barrier: drain staging (3 oldest VMEM), keep 4 mask loads in flight
#define TILE_BARRIER() do {                                                        \
        asm volatile("s_waitcnt vmcnt(4)\n\ts_barrier" ::: "memory");              \
        __builtin_amdgcn_sched_barrier(0);                                         \
    } while (0)

#define ITER_BODY(T, BUF, MU, MP) do {                                                   \
        TILE_BARRIER(); /* staging(T) drained; mask(T) still in flight */                \
        if ((T) + 1 < NT) {                                                              \
            STAGE((T) + 1, (BUF) ^ 1);                                                   \
            __builtin_amdgcn_sched_barrier(0); /* pin: staging before mask loads */      \
            LOADMASK(MP, (T) + 1);                                                       \
            __builtin_amdgcn_sched_barrier(0); /* pin: mask loads issued here */         \
        }                                                                                \
        const char* kb = lds_kv[BUF];                                                    \
        f32x4 s[4];                                                                      \
        _Pragma("unroll")                                                                \
        for (int kt = 0; kt < 4; ++kt) {                                                 \
            f32x4 a0 = (f32x4){0.f, 0.f, 0.f, 0.f};                                      \
            f32x4 a1 = (f32x4){0.f, 0.f, 0.f, 0.f};                                      \
            f32x4 a2 = (f32x4){0.f, 0.f, 0.f, 0.f};                                      \
            _Pragma("unroll")                                                            \
            for (int c = 0; c < 2; ++c) {                                                \
                const int krow = kt * 16 + lq;                                           \
                unsigned off = ((unsigned)(krow * 128 + (c * 32 + lg * 8) * 2))          \
                             ^ ((unsigned)((krow & 7) << 4));                            \
                bf16x8 khf = *(const bf16x8*)(kb + off);                                 \
                bf16x8 klf = *(const bf16x8*)(kb + 8192 + off);                          \
                /* swapped operands: S^T = K * Q^T; 3 independent 2-chains */            \
                a0 = __builtin_amdgcn_mfma_f32_16x16x32_bf16(khf, qh[c], a0, 0, 0, 0);   \
                a1 = __builtin_amdgcn_mfma_f32_16x16x32_bf16(klf, qh[c], a1, 0, 0, 0);   \
                a2 = __builtin_amdgcn_mfma_f32_16x16x32_bf16(khf, ql[c], a2, 0, 0, 0);   \
            }                                                                            \
            s[kt] = (a0 + a1) + a2;                                                      \
        }                                                                                \
        /* fixed-base softmax numerator + mask -> P (4 consecutive kv per kt, b64) */    \
        {                                                                                \
            unsigned short* pw = &lds_p[w][0];                                           \
            const unsigned pswz = (unsigned)((lq & 7) << 4);                             \
            _Pragma("unroll")                                                            \
            for (int kt = 0; kt < 4; ++kt) {                                             \
                float p0 = exp2f(s[kt][0]);                                              \
                float p1 = exp2f(s[kt][1]);                                              \
                float p2 = exp2f(s[kt][2]);                                              \
                float p3 = exp2f(s[kt][3]);                                              \
                l_acc += (p0 + p1) + (p2 + p3);                                          \
                unsigned w0 = cvtpk_bf16(p0 * MU[kt][0], p1 * MU[kt][1]);                \
                unsigned w1 = cvtpk_bf16(p2 * MU[kt][2], p3 * MU[kt][3]);                \
                unsigned off = ((unsigned)(lq * 128 + kt * 32 + lg * 8)) ^ pswz;         \
                u32x2 wv; wv[0] = w0; wv[1] = w1;                                        \
                *(u32x2*)((char*)pw + off) = wv;                                         \
            }                                                                            \
        }                                                                                \
        /* PV: P from wave-private LDS (b128), V^T frags from shared LDS blob */         \
        _Pragma("unroll")                                                                \
        for (int kc = 0; kc < 2; ++kc) {                                                 \
            unsigned poff = ((unsigned)(lq * 128 + (kc * 32 + lg * 8) * 2))              \
                          ^ ((unsigned)((lq & 7) << 4));                                 \
            bf16x8 pa = *(const bf16x8*)((const char*)&lds_p[w][0] + poff);              \
            _Pragma("unroll")                                                            \
            for (int dt = 0; dt < 4; ++dt) {                                             \
                const int drow = dt * 16 + lq;                                           \
                unsigned voff = 16384 +                                                  \
                    (((unsigned)(drow * 128 + (kc * 32 + lg * 8) * 2))                   \
                     ^ ((unsigned)((drow & 7) << 4)));                                   \
                bf16x8 vb = *(const bf16x8*)(kb + voff);                                 \
                o_acc[dt] = __builtin_amdgcn_mfma_f32_16x16x32_bf16(pa, vb, o_acc[dt],   \
                                                                    0, 0, 0);            \
            }                                                                            \
        }                                                                                \
    } while (0)

    float4_t mA[4], mB[4];
    STAGE(0, 0);
    __builtin_amdgcn_sched_barrier(0);
    LOADMASK(mA, 0);
    __builtin_amdgcn_sched_barrier(0);

    for (int t = 0; t < NT; t += 2) {
        ITER_BODY(t, 0, mA, mB);
        ITER_BODY(t + 1, 1, mB, mA);
    }

    // ---- epilogue: l lives at q=lq; reduce across lg, redistribute to o_acc rows ----
    l_acc += __shfl_xor(l_acc, 16);
    l_acc += __shfl_xor(l_acc, 32);
    if (lane < 16) lds_l[w][lane] = l_acc;
    __builtin_amdgcn_sched_barrier(0);
#pragma unroll
    for (int r = 0; r < 4; ++r) {
        const float inv = 1.0f / lds_l[w][lg * 4 + r];
#pragma unroll
        for (int dt = 0; dt < 4; ++dt) {
            op[(size_t)(lg * 4 + r) * Dn + dt * 16 + lq] = o_acc[dt][r] * inv;
        }
    }
#undef STAGE
#undef LOADMASK
#undef TILE_BARRIER
#undef ITER_BODY
}

// ---------------- fallback (self-contained, used if ws too small) ----------------
__global__ __launch_bounds__(256) void attn_drop_fallback(
    const float* __restrict__ Q, const float* __restrict__ K,
    const float* __restrict__ V, const float* __restrict__ Msk,
    float* __restrict__ Out)
{
    __shared__ unsigned short lds_kh[64 * 64];
    __shared__ unsigned short lds_kl[64 * 64];
    __shared__ unsigned short lds_v[64 * 64];
    __shared__ unsigned short lds_p[4][16 * 64];

    const int tid  = threadIdx.x;
    const int lane = tid & 63;
    const int w    = tid >> 6;
    const int lq   = lane & 15;
    const int lg   = lane >> 4;
    const int q0 = blockIdx.x * 64;
    const int bh = blockIdx.y;
    const size_t qkv_base = (size_t)bh * Sn * Dn;
    const float* qp = Q + qkv_base;
    const float* kp = K + qkv_base;
    const float* vp = V + qkv_base;
    const float* mbase = Msk + (size_t)bh * Sn * Sn + (size_t)(q0 + w * 16) * Sn;
    float* op = Out + qkv_base + (size_t)(q0 + w * 16) * Dn;
    const float SQRT2 = 1.41421356237f;
    const float LOG2E = 1.44269504089f;

    bf16x8 qh[2], ql[2];
    {
        const float* qrow = qp + (size_t)(q0 + w * 16 + lq) * Dn + lg * 8;
#pragma unroll
        for (int c = 0; c < 2; ++c) {
            float4_t f0 = *(const float4_t*)(qrow + c * 32);
            float4_t f1 = *(const float4_t*)(qrow + c * 32 + 4);
            float fv[8] = {f0[0], f0[1], f0[2], f0[3], f1[0], f1[1], f1[2], f1[3]};
            bf16x8 th, tl;
#pragma unroll
            for (int j = 0; j < 8; ++j) {
                short h = f2bf(fv[j]);
                th[j] = h; tl[j] = f2bf(fv[j] - bf2f(h));
            }
            qh[c] = th; ql[c] = tl;
        }
    }
    float m_st[4], l_st[4];
    f32x4 o_acc[4];
#pragma unroll
    for (int r = 0; r < 4; ++r) { m_st[r] = -INFINITY; l_st[r] = 0.0f; }
#pragma unroll
    for (int dt = 0; dt < 4; ++dt) o_acc[dt] = (f32x4){0.f, 0.f, 0.f, 0.f};

    for (int t = 0; t < NT; ++t) {
        const int kv0 = t * 64;
        __syncthreads();
        {
            const int r  = tid >> 2;
            const int dc = (tid & 3) * 16;
            const float* krow = kp + (size_t)(kv0 + r) * Dn + dc;
            float4_t k0 = ((const float4_t*)krow)[0];
            float4_t k1 = ((const float4_t*)krow)[1];
            float4_t k2 = ((const float4_t*)krow)[2];
            float4_t k3 = ((const float4_t*)krow)[3];
            float fv[16] = {k0[0],k0[1],k0[2],k0[3], k1[0],k1[1],k1[2],k1[3],
                            k2[0],k2[1],k2[2],k2[3], k3[0],k3[1],k3[2],k3[3]};
            bf16x8 ha, hb, la, lb;
#pragma unroll
            for (int j = 0; j < 8; ++j) {
                short h = f2bf(fv[j]);
                ha[j] = h; la[j] = f2bf(fv[j] - bf2f(h));
                short h2 = f2bf(fv[j + 8]);
                hb[j] = h2; lb[j] = f2bf(fv[j + 8] - bf2f(h2));
            }
            const unsigned base = (unsigned)(r * 128 + dc * 2);
            const unsigned swz  = (unsigned)((r & 7) << 4);
            *(bf16x8*)((char*)lds_kh + ((base) ^ swz))      = ha;
            *(bf16x8*)((char*)lds_kh + ((base + 16) ^ swz)) = hb;
            *(bf16x8*)((char*)lds_kl + ((base) ^ swz))      = la;
            *(bf16x8*)((char*)lds_kl + ((base + 16) ^ swz)) = lb;
        }
        {
            const int r2 = (tid & 31) * 2;
            const int d0 = (tid >> 5) * 8;
            const float* v0 = vp + (size_t)(kv0 + r2) * Dn + d0;
            float4_t a0 = ((const float4_t*)v0)[0];
            float4_t a1 = ((const float4_t*)v0)[1];
            float4_t b0 = ((const float4_t*)(v0 + Dn))[0];
            float4_t b1 = ((const float4_t*)(v0 + Dn))[1];
            float av[8] = {a0[0],a0[1],a0[2],a0[3], a1[0],a1[1],a1[2],a1[3]};
            float bv[8] = {b0[0],b0[1],b0[2],b0[3], b1[0],b1[1],b1[2],b1[3]};
#pragma unroll
            for (int j = 0; j < 8; ++j) {
                const int d = d0 + j;
                unsigned wv = ((unsigned)(unsigned short)f2bf(av[j]))
                            | (((unsigned)(unsigned short)f2bf(bv[j])) << 16);
                unsigned off = ((unsigned)(d * 128 + r2 * 2)) ^ ((unsigned)((d & 7) << 4));
                *(unsigned*)((char*)lds_v + off) = wv;
            }
        }
        __syncthreads();
        f32x4 s[4];
#pragma unroll
        for (int kt = 0; kt < 4; ++kt) {
            f32x4 acc = (f32x4){0.f, 0.f, 0.f, 0.f};
#pragma unroll
            for (int c = 0; c < 2; ++c) {
                const int krow = kt * 16 + lq;
                unsigned off = ((unsigned)(krow * 128 + (c * 32 + lg * 8) * 2))
                             ^ ((unsigned)((krow & 7) << 4));
                bf16x8 khf = *(const bf16x8*)((const char*)lds_kh + off);
                bf16x8 klf = *(const bf16x8*)((const char*)lds_kl + off);
                acc = __builtin_amdgcn_mfma_f32_16x16x32_bf16(qh[c], khf, acc, 0, 0, 0);
                acc = __builtin_amdgcn_mfma_f32_16x16x32_bf16(qh[c], klf, acc, 0, 0, 0);
                acc = __builtin_amdgcn_mfma_f32_16x16x32_bf16(ql[c], khf, acc, 0, 0, 0);
            }
            s[kt] = acc * SQRT2;
        }
        float pbuf[4][4];
#pragma unroll
        for (int r = 0; r < 4; ++r) {
            float mx = fmaxf(fmaxf(s[0][r], s[1][r]), fmaxf(s[2][r], s[3][r]));
            mx = fmaxf(mx, __shfl_xor(mx, 1));
            mx = fmaxf(mx, __shfl_xor(mx, 2));
            mx = fmaxf(mx, __shfl_xor(mx, 4));
            mx = fmaxf(mx, __shfl_xor(mx, 8));
            const float mnew = fmaxf(m_st[r], mx);
            const float corr = exp2f((m_st[r] - mnew) * LOG2E);
            m_st[r] = mnew;
            float psum = 0.f;
#pragma unroll
            for (int kt = 0; kt < 4; ++kt) {
                float p = exp2f((s[kt][r] - mnew) * LOG2E);
                pbuf[kt][r] = p;
                psum += p;
            }
            l_st[r] = l_st[r] * corr + psum;
#pragma unroll
            for (int dt = 0; dt < 4; ++dt) o_acc[dt][r] *= corr;
        }
        {
            unsigned short* pw = &lds_p[w][0];
#pragma unroll
            for (int r = 0; r < 4; ++r) {
                const int row = lg * 4 + r;
                const float* mp = mbase + (size_t)row * Sn + kv0;
#pragma unroll
                for (int kt = 0; kt < 4; ++kt) {
                    float mv = mp[kt * 16 + lq];
                    float pm = pbuf[kt][r] * mv;
                    unsigned off = ((unsigned)(row * 128 + (kt * 16 + lq) * 2))
                                 ^ ((unsigned)((row & 7) << 4));
                    *(unsigned short*)((char*)pw + off) = (unsigned short)f2bf(pm);
                }
            }
        }
        __syncthreads();
#pragma unroll
        for (int kc = 0; kc < 2; ++kc) {
            unsigned poff = ((unsigned)(lq * 128 + (kc * 32 + lg * 8) * 2))
                          ^ ((unsigned)((lq & 7) << 4));
            bf16x8 pa = *(const bf16x8*)((const char*)&lds_p[w][0] + poff);
#pragma unroll
            for (int dt = 0; dt < 4; ++dt) {
                const int drow = dt * 16 + lq;
                unsigned voff = ((unsigned)(drow * 128 + (kc * 32 + lg * 8) * 2))
                              ^ ((unsigned)((drow & 7) << 4));
                bf16x8 vb = *(const bf16x8*)((const char*)lds_v + voff);
                o_acc[dt] = __builtin_amdgcn_mfma_f32_16x16x32_bf16(pa, vb, o_acc[dt], 0, 0, 0);
            }
        }
    }
#pragma unroll
    for (int r = 0; r < 4; ++r) {
        float ls = l_st[r];
        ls += __shfl_xor(ls, 1);
        ls += __shfl_xor(ls, 2);
        ls += __shfl_xor(ls, 4);
        ls += __shfl_xor(ls, 8);
        const float inv = 1.0f / ls;
#pragma unroll
        for (int dt = 0; dt < 4; ++dt) {
            op[(size_t)(lg * 4 + r) * Dn + dt * 16 + lq] = o_acc[dt][r] * inv;
        }
    }
}

extern "C" void kernel_launch(void* const* d_in, const int* in_sizes, int n_in,
                              void* d_out, int out_size, void* d_ws, size_t ws_size,
                              hipStream_t stream) {
    const float* q   = (const float*)d_in[0];
    const float* k   = (const float*)d_in[1];
    const float* v   = (const float*)d_in[2];
    const float* msk = (const float*)d_in[3];
    float* out = (float*)d_out;

    if (ws_size >= WS_NEED) {
        prepass_kernel<<<dim3(Bn * Hn * NT), dim3(256), 0, stream>>>(k, v, (char*)d_ws);
        // 512-thread blocks: 8 waves share one staged blob; 128 q-rows/block
        attn_main_kernel<<<dim3(Bn * Hn, Sn / 128), dim3(512), 0, stream>>>(
            q, msk, (const char*)d_ws, out);
    } else {
        attn_drop_fallback<<<dim3(Sn / 64, Bn * Hn), dim3(256), 0, stream>>>(
            q, k, v, msk, out);
    }
}

// Round 14
// 315.045 us; speedup vs baseline: 1.1194x; 1.0571x over previous
//
#include <hip/hip_runtime.h>

#define Bn 4
#define Hn 16
#define Sn 2048
#define Dn 64
#define NT (Sn / 64)
#define BLOB 16384
#define WS_NEED ((size_t)Bn * Hn * NT * BLOB)

typedef __attribute__((ext_vector_type(8))) short bf16x8;
typedef __attribute__((ext_vector_type(8))) _Float16 f16x8;
typedef __attribute__((ext_vector_type(4))) float f32x4;
typedef __attribute__((ext_vector_type(4))) float float4_t;
typedef __attribute__((ext_vector_type(2))) unsigned u32x2;

__device__ __forceinline__ short f2bf(float f) {
    union { float f; unsigned u; } v; v.f = f;
    unsigned r = v.u + 0x7fffu + ((v.u >> 16) & 1u);
    return (short)(r >> 16);
}
__device__ __forceinline__ unsigned cvtpk_bf16(float a, float b) {
    unsigned d;
    asm("v_cvt_pk_bf16_f32 %0, %1, %2" : "=v"(d) : "v"(a), "v"(b));
    return d;
}

// ---------------- pre-pass: K -> fp16 (single), V -> V^T bf16, LDS-image layout ----------------
// blob[bh*NT + t] (16 KB): [0,8K) K fp16 swizzled, [8K,16K) V^T bf16 swizzled.
// fp16 (11-bit mantissa) QK meets the error budget without a hi/lo split; V/P stay bf16
// (P = exp2(s) fixed-base reaches 2^90 -> needs bf16's 8-bit exponent).
__global__ __launch_bounds__(256) void prepass_kernel(
    const float* __restrict__ K, const float* __restrict__ V, char* __restrict__ ws)
{
    const int tid = threadIdx.x;
    const int kv0 = (blockIdx.x & (NT - 1)) * 64;
    char* blob = ws + (size_t)blockIdx.x * BLOB;
    const size_t kv_base = (size_t)(blockIdx.x >> 5) * Sn * Dn;

    {
        const int r  = tid >> 2;
        const int dc = (tid & 3) * 16;
        const float* krow = K + kv_base + (size_t)(kv0 + r) * Dn + dc;
        float4_t k0 = ((const float4_t*)krow)[0];
        float4_t k1 = ((const float4_t*)krow)[1];
        float4_t k2 = ((const float4_t*)krow)[2];
        float4_t k3 = ((const float4_t*)krow)[3];
        float fv[16] = {k0[0],k0[1],k0[2],k0[3], k1[0],k1[1],k1[2],k1[3],
                        k2[0],k2[1],k2[2],k2[3], k3[0],k3[1],k3[2],k3[3]};
        f16x8 ha, hb;
#pragma unroll
        for (int j = 0; j < 8; ++j) {
            ha[j] = (_Float16)fv[j];
            hb[j] = (_Float16)fv[j + 8];
        }
        const unsigned base = (unsigned)(r * 128 + dc * 2);
        const unsigned swz  = (unsigned)((r & 7) << 4);
        *(f16x8*)(blob + ((base) ^ swz))      = ha;
        *(f16x8*)(blob + ((base + 16) ^ swz)) = hb;
    }
    {
        const int r2 = (tid & 31) * 2;
        const int d0 = (tid >> 5) * 8;
        const float* v0 = V + kv_base + (size_t)(kv0 + r2) * Dn + d0;
        float4_t a0 = ((const float4_t*)v0)[0];
        float4_t a1 = ((const float4_t*)v0)[1];
        float4_t b0 = ((const float4_t*)(v0 + Dn))[0];
        float4_t b1 = ((const float4_t*)(v0 + Dn))[1];
        float av[8] = {a0[0],a0[1],a0[2],a0[3], a1[0],a1[1],a1[2],a1[3]};
        float bv[8] = {b0[0],b0[1],b0[2],b0[3], b1[0],b1[1],b1[2],b1[3]};
#pragma unroll
        for (int j = 0; j < 8; ++j) {
            const int d = d0 + j;
            unsigned wv = ((unsigned)(unsigned short)f2bf(av[j]))
                        | (((unsigned)(unsigned short)f2bf(bv[j])) << 16);
            unsigned off = ((unsigned)(d * 128 + r2 * 2)) ^ ((unsigned)((d & 7) << 4));
            *(unsigned*)(blob + 8192 + off) = wv;
        }
    }
}

// ---------------- main attention kernel: R13 shell + single-fp16 QK^T ----------------
// 8 waves/512 threads share one staged 16 KB blob; swapped S^T QK (mfma_f32_16x16x32_f16,
// ONE MFMA per (kt,c)); fixed-base softmax; cvt_pk bf16 P-writes; PV in bf16; counted barrier.
// LDS ~48 KB -> up to 3 blocks/CU. QK ds_reads halved vs R13; QK MFMAs 24 -> 8.
__global__ __launch_bounds__(512, 4) void attn_main_kernel(
    const float* __restrict__ Q, const float* __restrict__ Msk,
    const char* __restrict__ ws, float* __restrict__ Out)
{
    __shared__ char lds_kv[2][BLOB];               // double-buffered tile blob (shared by 8 waves)
    __shared__ unsigned short lds_p[8][16 * 64];   // per-wave P tile (wave-private)
    __shared__ float lds_l[8][16];                 // per-wave denom redistribute (epilogue)

    const int tid  = threadIdx.x;
    const int lane = tid & 63;
    const int w    = tid >> 6;        // 0..7
    const int lq   = lane & 15;
    const int lg   = lane >> 4;

    const int bh = blockIdx.x;        // bh-major: XCD = bh % 8
    const int q0 = blockIdx.y * 128;  // 128 q-rows per block

    const float* qp   = Q + (size_t)bh * Sn * Dn;
    const float* mrow = Msk + (size_t)bh * Sn * Sn + (size_t)(q0 + w * 16 + lq) * Sn;
    const char* ws_bh = ws + (size_t)bh * NT * BLOB;
    float* op = Out + (size_t)bh * Sn * Dn + (size_t)(q0 + w * 16) * Dn;

    const float QSCALE = 2.0402789f;  // sqrt(2) * log2(e): logits directly in log2 domain

    // ---- Q fragments, single fp16, pre-scaled (MFMA B operand) ----
    f16x8 qf[2];
    {
        const float* qrow = qp + (size_t)(q0 + w * 16 + lq) * Dn + lg * 8;
#pragma unroll
        for (int c = 0; c < 2; ++c) {
            float4_t f0 = *(const float4_t*)(qrow + c * 32);
            float4_t f1 = *(const float4_t*)(qrow + c * 32 + 4);
            float fv[8] = {f0[0], f0[1], f0[2], f0[3], f1[0], f1[1], f1[2], f1[3]};
            f16x8 tf;
#pragma unroll
            for (int j = 0; j < 8; ++j) tf[j] = (_Float16)(fv[j] * QSCALE);
            qf[c] = tf;
        }
    }

    float l_acc = 0.0f;   // per-lane partial denominator for q = lq
    f32x4 o_acc[4];
#pragma unroll
    for (int dt = 0; dt < 4; ++dt) o_acc[dt] = (f32x4){0.f, 0.f, 0.f, 0.f};

// 8 waves x 2 KB each = 16 KB blob
#define STAGE(TSRC, BUFIDX) do {                                                   \
        const char* _src = ws_bh + (size_t)(TSRC) * BLOB + w * 2048 + lane * 16;   \
        char* _dst = &lds_kv[BUFIDX][w * 2048];                                    \
        _Pragma("unroll")                                                          \
        for (int _i = 0; _i < 2; ++_i) {                                           \
            __builtin_amdgcn_global_load_lds(                                      \
                (const __attribute__((address_space(1))) void*)(_src + _i * 1024), \
                (__attribute__((address_space(3))) void*)(_dst + _i * 1024),       \
                16, 0, 0);                                                         \
        }                                                                          \
    } while (0)

// mask[q=lq][kv = T*64 + kt*16 + lg*4 .. +3] as one dwordx4 per kt
#define LOADMASK(MREG, TSRC) do {                                                  \
        _Pragma("unroll")                                                          \
        for (int _kt = 0; _kt < 4; ++_kt)                                          \
            MREG[_kt] = *(const float4_t*)(mrow + (TSRC) * 64 + _kt * 16 + lg * 4);\
    } while (0)

// counted barrier: drain staging (2 oldest VMEM), keep 4 mask loads in flight
#define TILE_BARRIER() do {                                                        \
        asm volatile("s_waitcnt vmcnt(4)\n\ts_barrier" ::: "memory");              \
        __builtin_amdgcn_sched_barrier(0);                                         \
    } while (0)

#define ITER_BODY(T, BUF, MU, MP) do {                                                   \
        TILE_BARRIER(); /* staging(T) drained; mask(T) still in flight */                \
        if ((T) + 1 < NT) {                                                              \
            STAGE((T) + 1, (BUF) ^ 1);                                                   \
            __builtin_amdgcn_sched_barrier(0); /* pin: staging before mask loads */      \
            LOADMASK(MP, (T) + 1);                                                       \
            __builtin_amdgcn_sched_barrier(0); /* pin: mask loads issued here */         \
        }                                                                                \
        const char* kb = lds_kv[BUF];                                                    \
        f32x4 s[4];                                                                      \
        _Pragma("unroll")                                                                \
        for (int kt = 0; kt < 4; ++kt) {                                                 \
            f32x4 acc = (f32x4){0.f, 0.f, 0.f, 0.f};                                     \
            _Pragma("unroll")                                                            \
            for (int c = 0; c < 2; ++c) {                                                \
                const int krow = kt * 16 + lq;                                           \
                unsigned off = ((unsigned)(krow * 128 + (c * 32 + lg * 8) * 2))          \
                             ^ ((unsigned)((krow & 7) << 4));                            \
                f16x8 khf = *(const f16x8*)(kb + off);                                   \
                /* swapped operands: S^T = K * Q^T, single fp16 MFMA */                  \
                acc = __builtin_amdgcn_mfma_f32_16x16x32_f16(khf, qf[c], acc, 0, 0, 0);  \
            }                                                                            \
            s[kt] = acc;                                                                 \
        }                                                                                \
        /* fixed-base softmax numerator + mask -> P (4 consecutive kv per kt, b64) */    \
        {                                                                                \
            unsigned short* pw = &lds_p[w][0];                                           \
            const unsigned pswz = (unsigned)((lq & 7) << 4);                             \
            _Pragma("unroll")                                                            \
            for (int kt = 0; kt < 4; ++kt) {                                             \
                float p0 = exp2f(s[kt][0]);                                              \
                float p1 = exp2f(s[kt][1]);                                              \
                float p2 = exp2f(s[kt][2]);                                              \
                float p3 = exp2f(s[kt][3]);                                              \
                l_acc += (p0 + p1) + (p2 + p3);                                          \
                unsigned w0 = cvtpk_bf16(p0 * MU[kt][0], p1 * MU[kt][1]);                \
                unsigned w1 = cvtpk_bf16(p2 * MU[kt][2], p3 * MU[kt][3]);                \
                unsigned off = ((unsigned)(lq * 128 + kt * 32 + lg * 8)) ^ pswz;         \
                u32x2 wv; wv[0] = w0; wv[1] = w1;                                        \
                *(u32x2*)((char*)pw + off) = wv;                                         \
            }                                                                            \
        }                                                                                \
        /* PV (bf16): P from wave-private LDS (b128), V^T frags from shared blob */      \
        _Pragma("unroll")                                                                \
        for (int kc = 0; kc < 2; ++kc) {                                                 \
            unsigned poff = ((unsigned)(lq * 128 + (kc * 32 + lg * 8) * 2))              \
                          ^ ((unsigned)((lq & 7) << 4));                                 \
            bf16x8 pa = *(const bf16x8*)((const char*)&lds_p[w][0] + poff);              \
            _Pragma("unroll")                                                            \
            for (int dt = 0; dt < 4; ++dt) {                                             \
                const int drow = dt * 16 + lq;                                           \
                unsigned voff = 8192 +                                                   \
                    (((unsigned)(drow * 128 + (kc * 32 + lg * 8) * 2))                   \
                     ^ ((unsigned)((drow & 7) << 4)));                                   \
                bf16x8 vb = *(const bf16x8*)(kb + voff);                                 \
                o_acc[dt] = __builtin_amdgcn_mfma_f32_16x16x32_bf16(pa, vb, o_acc[dt],   \
                                                                    0, 0, 0);            \
            }                                                                            \
        }                                                                                \
    } while (0)

    float4_t mA[4], mB[4];
    STAGE(0, 0);
    __builtin_amdgcn_sched_barrier(0);
    LOADMASK(mA, 0);
    __builtin_amdgcn_sched_barrier(0);

    for (int t = 0; t < NT; t += 2) {
        ITER_BODY(t, 0, mA, mB);
        ITER_BODY(t + 1, 1, mB, mA);
    }

    // ---- epilogue: l lives at q=lq; reduce across lg, redistribute to o_acc rows ----
    l_acc += __shfl_xor(l_acc, 16);
    l_acc += __shfl_xor(l_acc, 32);
    if (lane < 16) lds_l[w][lane] = l_acc;
    __builtin_amdgcn_sched_barrier(0);
#pragma unroll
    for (int r = 0; r < 4; ++r) {
        const float inv = 1.0f / lds_l[w][lg * 4 + r];
#pragma unroll
        for (int dt = 0; dt < 4; ++dt) {
            op[(size_t)(lg * 4 + r) * Dn + dt * 16 + lq] = o_acc[dt][r] * inv;
        }
    }
#undef STAGE
#undef LOADMASK
#undef TILE_BARRIER
#undef ITER_BODY
}

// ---------------- fallback (self-contained, used if ws too small) ----------------
__global__ __launch_bounds__(256) void attn_drop_fallback(
    const float* __restrict__ Q, const float* __restrict__ K,
    const float* __restrict__ V, const float* __restrict__ Msk,
    float* __restrict__ Out)
{
    __shared__ unsigned short lds_kf[64 * 64];
    __shared__ unsigned short lds_v[64 * 64];
    __shared__ unsigned short lds_p[4][16 * 64];

    const int tid  = threadIdx.x;
    const int lane = tid & 63;
    const int w    = tid >> 6;
    const int lq   = lane & 15;
    const int lg   = lane >> 4;
    const int q0 = blockIdx.x * 64;
    const int bh = blockIdx.y;
    const size_t qkv_base = (size_t)bh * Sn * Dn;
    const float* qp = Q + qkv_base;
    const float* kp = K + qkv_base;
    const float* vp = V + qkv_base;
    const float* mbase = Msk + (size_t)bh * Sn * Sn + (size_t)(q0 + w * 16) * Sn;
    float* op = Out + qkv_base + (size_t)(q0 + w * 16) * Dn;
    const float QSCALE = 2.0402789f;

    f16x8 qf[2];
    {
        const float* qrow = qp + (size_t)(q0 + w * 16 + lq) * Dn + lg * 8;
#pragma unroll
        for (int c = 0; c < 2; ++c) {
            float4_t f0 = *(const float4_t*)(qrow + c * 32);
            float4_t f1 = *(const float4_t*)(qrow + c * 32 + 4);
            float fv[8] = {f0[0], f0[1], f0[2], f0[3], f1[0], f1[1], f1[2], f1[3]};
            f16x8 tf;
#pragma unroll
            for (int j = 0; j < 8; ++j) tf[j] = (_Float16)(fv[j] * QSCALE);
            qf[c] = tf;
        }
    }
    float l_st[4];
    f32x4 o_acc[4];
#pragma unroll
    for (int r = 0; r < 4; ++r) l_st[r] = 0.0f;
#pragma unroll
    for (int dt = 0; dt < 4; ++dt) o_acc[dt] = (f32x4){0.f, 0.f, 0.f, 0.f};

    for (int t = 0; t < NT; ++t) {
        const int kv0 = t * 64;
        __syncthreads();
        {
            const int r  = tid >> 2;
            const int dc = (tid & 3) * 16;
            const float* krow = kp + (size_t)(kv0 + r) * Dn + dc;
            float4_t k0 = ((const float4_t*)krow)[0];
            float4_t k1 = ((const float4_t*)krow)[1];
            float4_t k2 = ((const float4_t*)krow)[2];
            float4_t k3 = ((const float4_t*)krow)[3];
            float fv[16] = {k0[0],k0[1],k0[2],k0[3], k1[0],k1[1],k1[2],k1[3],
                            k2[0],k2[1],k2[2],k2[3], k3[0],k3[1],k3[2],k3[3]};
            f16x8 ha, hb;
#pragma unroll
            for (int j = 0; j < 8; ++j) {
                ha[j] = (_Float16)fv[j];
                hb[j] = (_Float16)fv[j + 8];
            }
            const unsigned base = (unsigned)(r * 128 + dc * 2);
            const unsigned swz  = (unsigned)((r & 7) << 4);
            *(f16x8*)((char*)lds_kf + ((base) ^ swz))      = ha;
            *(f16x8*)((char*)lds_kf + ((base + 16) ^ swz)) = hb;
        }
        {
            const int r2 = (tid & 31) * 2;
            const int d0 = (tid >> 5) * 8;
            const float* v0 = vp + (size_t)(kv0 + r2) * Dn + d0;
            float4_t a0 = ((const float4_t*)v0)[0];
            float4_t a1 = ((const float4_t*)v0)[1];
            float4_t b0 = ((const float4_t*)(v0 + Dn))[0];
            float4_t b1 = ((const float4_t*)(v0 + Dn))[1];
            float av[8] = {a0[0],a0[1],a0[2],a0[3], a1[0],a1[1],a1[2],a1[3]};
            float bv[8] = {b0[0],b0[1],b0[2],b0[3], b1[0],b1[1],b1[2],b1[3]};
#pragma unroll
            for (int j = 0; j < 8; ++j) {
                const int d = d0 + j;
                unsigned wv = ((unsigned)(unsigned short)f2bf(av[j]))
                            | (((unsigned)(unsigned short)f2bf(bv[j])) << 16);
                unsigned off = ((unsigned)(d * 128 + r2 * 2)) ^ ((unsigned)((d & 7) << 4));
                *(unsigned*)((char*)lds_v + off) = wv;
            }
        }
        __syncthreads();
        f32x4 s[4];
#pragma unroll
        for (int kt = 0; kt < 4; ++kt) {
            f32x4 acc = (f32x4){0.f, 0.f, 0.f, 0.f};
#pragma unroll
            for (int c = 0; c < 2; ++c) {
                const int krow = kt * 16 + lq;
                unsigned off = ((unsigned)(krow * 128 + (c * 32 + lg * 8) * 2))
                             ^ ((unsigned)((krow & 7) << 4));
                f16x8 khf = *(const f16x8*)((const char*)lds_kf + off);
                acc = __builtin_amdgcn_mfma_f32_16x16x32_f16(khf, qf[c], acc, 0, 0, 0);
            }
            s[kt] = acc;
        }
        // NOTE: swapped operands -> lane holds q=lq, kv=kt*16+lg*4+r
        {
            unsigned short* pw = &lds_p[w][0];
            const unsigned pswz = (unsigned)((lq & 7) << 4);
            const float* mp = mbase + (size_t)lq * Sn + kv0;
#pragma unroll
            for (int kt = 0; kt < 4; ++kt) {
                float p0 = exp2f(s[kt][0]) * mp[kt * 16 + lg * 4 + 0];
                float p1 = exp2f(s[kt][1]) * mp[kt * 16 + lg * 4 + 1];
                float p2 = exp2f(s[kt][2]) * mp[kt * 16 + lg * 4 + 2];
                float p3 = exp2f(s[kt][3]) * mp[kt * 16 + lg * 4 + 3];
                l_st[0] += exp2f(s[kt][0]) + exp2f(s[kt][1])
                         + exp2f(s[kt][2]) + exp2f(s[kt][3]);
                unsigned w0 = cvtpk_bf16(p0, p1);
                unsigned w1 = cvtpk_bf16(p2, p3);
                unsigned off = ((unsigned)(lq * 128 + kt * 32 + lg * 8)) ^ pswz;
                u32x2 wv; wv[0] = w0; wv[1] = w1;
                *(u32x2*)((char*)pw + off) = wv;
            }
        }
        __syncthreads();
#pragma unroll
        for (int kc = 0; kc < 2; ++kc) {
            unsigned poff = ((unsigned)(lq * 128 + (kc * 32 + lg * 8) * 2))
                          ^ ((unsigned)((lq & 7) << 4));
            bf16x8 pa = *(const bf16x8*)((const char*)&lds_p[w][0] + poff);
#pragma unroll
            for (int dt = 0; dt < 4; ++dt) {
                const int drow = dt * 16 + lq;
                unsigned voff = ((unsigned)(drow * 128 + (kc * 32 + lg * 8) * 2))
                              ^ ((unsigned)((drow & 7) << 4));
                bf16x8 vb = *(const bf16x8*)((const char*)lds_v + voff);
                o_acc[dt] = __builtin_amdgcn_mfma_f32_16x16x32_bf16(pa, vb, o_acc[dt], 0, 0, 0);
            }
        }
    }
    // l lives at q=lq per lane
    {
        float l_acc = l_st[0];
        l_acc += __shfl_xor(l_acc, 16);
        l_acc += __shfl_xor(l_acc, 32);
        __shared__ float lds_l[4][16];
        if (lane < 16) lds_l[w][lane] = l_acc;
        __syncthreads();
#pragma unroll
        for (int r = 0; r < 4; ++r) {
            const float inv = 1.0f / lds_l[w][lg * 4 + r];
#pragma unroll
            for (int dt = 0; dt < 4; ++dt) {
                op[(size_t)(lg * 4 + r) * Dn + dt * 16 + lq] = o_acc[dt][r] * inv;
            }
        }
    }
}

extern "C" void kernel_launch(void* const* d_in, const int* in_sizes, int n_in,
                              void* d_out, int out_size, void* d_ws, size_t ws_size,
                              hipStream_t stream) {
    const float* q   = (const float*)d_in[0];
    const float* k   = (const float*)d_in[1];
    const float* v   = (const float*)d_in[2];
    const float* msk = (const float*)d_in[3];
    float* out = (float*)d_out;

    if (ws_size >= WS_NEED) {
        prepass_kernel<<<dim3(Bn * Hn * NT), dim3(256), 0, stream>>>(k, v, (char*)d_ws);
        attn_main_kernel<<<dim3(Bn * Hn, Sn / 128), dim3(512), 0, stream>>>(
            q, msk, (const char*)d_ws, out);
    } else {
        attn_drop_fallback<<<dim3(Sn / 64, Bn * Hn), dim3(256), 0, stream>>>(
            q, k, v, msk, out);
    }
}